// Round 2
// baseline (485.503 us; speedup 1.0000x reference)
//
#include <hip/hip_runtime.h>

#define D_MODEL 1024
#define D_STATE 64
#define CHUNK   256

// One thread owns one d-column of one (b,chunk) scan; h[64] + A[64] in VGPRs.
// B[t,:], C[t,:] are wave-uniform -> scalar loads (SGPRs), no LDS at all.
// grid = 64 (b,c) x 16 d-groups = 1024 blocks of 64 threads (1 wave each).
__global__ __launch_bounds__(64, 1)
void YvParallelScan_kernel(const float* __restrict__ u,
                           const float* __restrict__ B,
                           const float* __restrict__ C,
                           const float* __restrict__ A_log,
                           float* __restrict__ out) {
    const int bc = blockIdx.x >> 4;            // 0..63  (b*16 + c)
    const int dg = blockIdx.x & 15;            // d-group of 64
    const int d  = dg * 64 + threadIdx.x;      // 0..1023
    const int rowbase = bc * CHUNK;            // b*4096 + c*256

    float a[D_STATE], h[D_STATE];
#pragma unroll
    for (int n = 0; n < D_STATE; ++n) {
        a[n] = -__expf(A_log[n * D_MODEL + d]);
        h[n] = 0.f;
    }

    const float* uptr = u   + (size_t)rowbase * D_MODEL + d;
    float*       optr = out + (size_t)rowbase * D_MODEL + d;
    const float* Brow = B   + (size_t)rowbase * D_STATE;   // wave-uniform rows
    const float* Crow = C   + (size_t)rowbase * D_STATE;

    // software prefetch of x two timesteps ahead
    float xa = uptr[0];
    float xb = uptr[D_MODEL];

    for (int t = 0; t < CHUNK; ++t) {
        const int tp = (t + 2 < CHUNK) ? (t + 2) : (CHUNK - 1);
        float xn = uptr[(size_t)tp * D_MODEL];   // issue early, used 2 iters later

        const float x = xa;
        float acc0 = 0.f, acc1 = 0.f, acc2 = 0.f, acc3 = 0.f;

#pragma unroll
        for (int n = 0; n < D_STATE; n += 4) {
            // uniform addresses -> s_load into SGPRs; one SGPR operand per VALU op
            float b0 = Brow[t * D_STATE + n + 0];
            float b1 = Brow[t * D_STATE + n + 1];
            float b2 = Brow[t * D_STATE + n + 2];
            float b3 = Brow[t * D_STATE + n + 3];
            float c0 = Crow[t * D_STATE + n + 0];
            float c1 = Crow[t * D_STATE + n + 1];
            float c2 = Crow[t * D_STATE + n + 2];
            float c3 = Crow[t * D_STATE + n + 3];

            h[n + 0] = a[n + 0] * h[n + 0] + b0 * x;
            h[n + 1] = a[n + 1] * h[n + 1] + b1 * x;
            h[n + 2] = a[n + 2] * h[n + 2] + b2 * x;
            h[n + 3] = a[n + 3] * h[n + 3] + b3 * x;

            acc0 = fmaf(c0, h[n + 0], acc0);
            acc1 = fmaf(c1, h[n + 1], acc1);
            acc2 = fmaf(c2, h[n + 2], acc2);
            acc3 = fmaf(c3, h[n + 3], acc3);
        }

        optr[(size_t)t * D_MODEL] = (acc0 + acc1) + (acc2 + acc3);
        xa = xb;
        xb = xn;
    }
}

extern "C" void kernel_launch(void* const* d_in, const int* in_sizes, int n_in,
                              void* d_out, int out_size, void* d_ws, size_t ws_size,
                              hipStream_t stream) {
    const float* u     = (const float*)d_in[0];
    // d_in[1] = delta, unused by the reference forward
    const float* B     = (const float*)d_in[2];
    const float* C     = (const float*)d_in[3];
    const float* A_log = (const float*)d_in[4];
    float* out = (float*)d_out;

    YvParallelScan_kernel<<<1024, 64, 0, stream>>>(u, B, C, A_log, out);
}

// Round 3
// 266.598 us; speedup vs baseline: 1.8211x; 1.8211x over previous
//
#include <hip/hip_runtime.h>

typedef float v4 __attribute__((ext_vector_type(4)));

#define D_MODEL 1024
#define D_STATE 64
#define CHUNK   256
#define TILE_T  64

// Block = one (bc, d-quarter): 256 threads = 4 waves.
// Wave ng owns n-slice [ng*16, ng*16+16); lane owns 4 consecutive d.
// h[16 n][4 d] per lane in VGPRs. B/C broadcast from LDS tiles (8 b128/t/wave).
// y = sum over n-waves via 2-slot LDS partials, 1 barrier/t, reducer rotates.
__global__ __launch_bounds__(256, 1)
void YvParallelScan_kernel(const float* __restrict__ u,
                           const float* __restrict__ B,
                           const float* __restrict__ C,
                           const float* __restrict__ A_log,
                           float* __restrict__ out) {
    __shared__ v4 sB[TILE_T * 16];     // 16 KB  [tl][n/4]
    __shared__ v4 sC[TILE_T * 16];     // 16 KB
    __shared__ v4 sP[2][4][64];        //  8 KB  [slot][wave][lane]

    const int bc   = blockIdx.x >> 2;          // 0..63
    const int dq   = blockIdx.x & 3;           // d-quarter
    const int tid  = threadIdx.x;
    const int ng   = tid >> 6;                 // wave = n-group
    const int lane = tid & 63;
    const int rowbase = bc * CHUNK;

    const v4* Bg = (const v4*)(B + (size_t)rowbase * D_STATE);
    const v4* Cg = (const v4*)(C + (size_t)rowbase * D_STATE);

    // lane's d-block: d = dq*256 + lane*4 .. +3   (v4 index dbase4)
    const int dbase4 = dq * 64 + lane;

    v4 a4[16], h4[16];
#pragma unroll
    for (int j = 0; j < 16; ++j) {
        const int n = ng * 16 + j;
        v4 al = ((const v4*)A_log)[n * 256 + dbase4];
        v4 na;
        na[0] = -__expf(al[0]); na[1] = -__expf(al[1]);
        na[2] = -__expf(al[2]); na[3] = -__expf(al[3]);
        a4[j] = na;
        v4 z = {0.f, 0.f, 0.f, 0.f};
        h4[j] = z;
    }

    const v4* uptr = (const v4*)(u + (size_t)rowbase * D_MODEL) + dbase4;
    v4*       optr = (v4*)(out + (size_t)rowbase * D_MODEL) + dbase4;

    // x prefetch, depth 2
    v4 xa = uptr[0];
    v4 xb = uptr[256];

    for (int ti = 0; ti < CHUNK / TILE_T; ++ti) {
        // stage next 64-t tile of B,C (coalesced; prior tile's LDS reads all
        // completed before the last per-t barrier of the previous tile)
#pragma unroll
        for (int k = 0; k < 4; ++k) {
            sB[k * 256 + tid] = Bg[ti * 1024 + k * 256 + tid];
            sC[k * 256 + tid] = Cg[ti * 1024 + k * 256 + tid];
        }
        __syncthreads();

#pragma unroll 4
        for (int tl = 0; tl < TILE_T; ++tl) {
            const int t  = ti * TILE_T + tl;
            const int tp = (t + 2 < CHUNK) ? (t + 2) : (CHUNK - 1);
            v4 xn = uptr[(size_t)tp * 256];

            const v4 x = xa;
            v4 acc = {0.f, 0.f, 0.f, 0.f};
#pragma unroll
            for (int jj = 0; jj < 4; ++jj) {
                v4 b4 = sB[tl * 16 + ng * 4 + jj];   // broadcast ds_read_b128
                v4 c4 = sC[tl * 16 + ng * 4 + jj];
#pragma unroll
                for (int k = 0; k < 4; ++k) {
                    const int j = jj * 4 + k;
                    h4[j] = a4[j] * h4[j] + b4[k] * x;
                    acc  += c4[k] * h4[j];
                }
            }

            const int slot = t & 1;   // compile-time under unroll 4
            const int red  = t & 3;
            if (ng != red) sP[slot][ng][lane] = acc;
            __syncthreads();
            if (ng == red) {
                v4 s = acc;
#pragma unroll
                for (int w = 0; w < 4; ++w)
                    if (w != red) s += sP[slot][w][lane];
                optr[(size_t)t * 256] = s;
            }
            xa = xb; xb = xn;
        }
    }
}

extern "C" void kernel_launch(void* const* d_in, const int* in_sizes, int n_in,
                              void* d_out, int out_size, void* d_ws, size_t ws_size,
                              hipStream_t stream) {
    const float* u     = (const float*)d_in[0];
    // d_in[1] = delta, unused by the reference forward
    const float* B     = (const float*)d_in[2];
    const float* C     = (const float*)d_in[3];
    const float* A_log = (const float*)d_in[4];
    float* out = (float*)d_out;

    YvParallelScan_kernel<<<256, 256, 0, stream>>>(u, B, C, A_log, out);
}